// Round 8
// baseline (370.919 us; speedup 1.0000x reference)
//
#include <hip/hip_runtime.h>

// B=64 T=1024 D=512 H=512 O=128 HALF=256 ALPHA_M=0.8
// Pipeline:
//   gtab   : fix-up coefficient tables G1/G2 [32][512] f32
//   wcast  : w1/w2/wo fp32 -> bf16 (one-time)
//   cast   : x fp32 -> xb bf16
//   gemm1f : 8-wave, BK=32, 2-phase LDS staging with COUNTED vmcnt(4) (stage(t)
//            waited one full round after issue; stage(t+1) stays in flight across
//            the barrier) + in-LDS chunk scan -> mems + chunk states.
//   scanB  : sequential chunk-state combine -> D1/D2/DM prefix states
//   gemm2f : 8-wave blocks: fix-up in A-staging + MFMA + bias + sigmoid -> out fp32

#define B_    64
#define T_    1024
#define D_    512
#define H_    512
#define O_    128
#define HALF_ 256
#define CLEN  32
#define NC    32

typedef __attribute__((ext_vector_type(4))) float        f32x4;
typedef __attribute__((ext_vector_type(2))) float        f32x2;
typedef __attribute__((ext_vector_type(8))) short        s16x8;
typedef __attribute__((ext_vector_type(4))) unsigned int u32x4;
typedef __attribute__((ext_vector_type(2))) unsigned int u32x2;

__device__ __forceinline__ unsigned short f2bf(float f) {
    unsigned u = __float_as_uint(f);
    return (unsigned short)((u + 0x7fffu + ((u >> 16) & 1u)) >> 16);  // RNE
}
__device__ __forceinline__ unsigned packbf(float a, float b) {
    return (unsigned)f2bf(a) | ((unsigned)f2bf(b) << 16);
}
__device__ __forceinline__ float bflo(unsigned u) { return __uint_as_float(u << 16); }
__device__ __forceinline__ float bfu16(unsigned short u) {
    return __uint_as_float(((unsigned)u) << 16);
}
__device__ __forceinline__ float bfhi(unsigned u) { return __uint_as_float(u & 0xffff0000u); }
__device__ __forceinline__ float sigf(float x) { return 1.f / (1.f + __expf(-x)); }
__device__ __forceinline__ float guard(float dn) {
    if (fabsf(dn) < 1e-6f) dn = (dn < 0.f ? -1e-6f : 1e-6f);
    return dn;
}
__device__ __forceinline__ float pw32(float a) {  // a^32
    float t = a * a; t *= t; t *= t; t *= t; t *= t; return t;
}

typedef const __attribute__((address_space(1))) unsigned int gu32;
typedef __attribute__((address_space(3))) unsigned int      lu32;
__device__ __forceinline__ void gl_lds16(const void* g, void* l) {
    __builtin_amdgcn_global_load_lds((gu32*)g, (lu32*)l, 16, 0, 0);
}

// ---------------- gtab: G1[k][h] = c1(h)*(0.8^{k+1} - a1(h)^{k+1}), same G2 --------------
__global__ __launch_bounds__(256) void gtab_kernel(
    const float* __restrict__ tau1, const float* __restrict__ tau2,
    float* __restrict__ G1, float* __restrict__ G2)
{
    const int h = blockIdx.x * 256 + threadIdx.x;   // 0..511
    const float a1 = sigf(tau1[h]), a2 = sigf(tau2[h]);
    const float c1 = 0.2f * a1 / guard(0.8f - a1);
    const float c2 = 0.2f * a2 / guard(0.8f - a2);
    float pm = 1.f, p1 = 1.f, p2 = 1.f;
    for (int k = 0; k < CLEN; ++k) {
        pm *= 0.8f; p1 *= a1; p2 *= a2;
        G1[k * H_ + h] = c1 * (pm - p1);
        G2[k * H_ + h] = c2 * (pm - p2);
    }
}

// ---------------- wcast: w1/w2/wo fp32 -> bf16 packed (bit-identical RNE) ----------------
__global__ __launch_bounds__(256) void wcast_kernel(
    const float* __restrict__ w1, const float* __restrict__ w2,
    const float* __restrict__ wo,
    unsigned int* __restrict__ w1b, unsigned int* __restrict__ w2b,
    unsigned int* __restrict__ wob)
{
    const float* s; unsigned int* d; int n;
    if (blockIdx.y == 0)      { s = w1; d = w1b; n = H_ * HALF_; }
    else if (blockIdx.y == 1) { s = w2; d = w2b; n = H_ * HALF_; }
    else                      { s = wo; d = wob; n = O_ * H_;    }
    int i = (blockIdx.x * 256 + threadIdx.x) * 4;
    if (i >= n) return;
    f32x4 a = *(const f32x4*)(s + i);
    u32x2 p;
    p.x = packbf(a.x, a.y);
    p.y = packbf(a.z, a.w);
    *(u32x2*)(d + i / 2) = p;
}

// ---------------- cast: x fp32 -> xb bf16 (packed) ---------------------------------------
__global__ __launch_bounds__(256) void cast_kernel(const float* __restrict__ x,
                                                   unsigned int* __restrict__ xb) {
    size_t i = ((size_t)blockIdx.x * 256 + threadIdx.x) * 8;
    f32x4 a = *(const f32x4*)(x + i);
    f32x4 b = *(const f32x4*)(x + i + 4);
    u32x4 p;
    p.x = packbf(a.x, a.y); p.y = packbf(a.z, a.w);
    p.z = packbf(b.x, b.y); p.w = packbf(b.z, b.w);
    *(u32x4*)(xb + i / 2) = p;
}

// ---------------- gemm1f: BK=32 2-phase staging, counted vmcnt pipeline ------------------
// Phase layout (shorts, 16384/phase = 32 KB): As1 [0,4096) As2 [4096,8192)
// Bs1 [8192,12288) Bs2 [12288,16384). Tile = [kchunk 0..3][row 0..127][8 shorts].
// DMA: wave wv writes chunk wv>>1, rows (wv&1)*64+l (linear 1 KB/wave).
// ds_read: quarter qd reads chunk qd, lanes stride 16 B (conflict-free, R5-verified).
// Pipeline: stage(t) waited via vmcnt(4) one full round after issue; stage(t+1)
// remains in flight across the barrier (never vmcnt(0) in the loop).
__global__ __launch_bounds__(512, 4) void gemm1f_kernel(
    const unsigned short* __restrict__ xb,
    const unsigned short* __restrict__ w1b, const unsigned short* __restrict__ w2b,
    const float* __restrict__ b1, const float* __restrict__ tau1,
    const float* __restrict__ b2, const float* __restrict__ tau2,
    unsigned int* __restrict__ mems,
    float* __restrict__ Sd1, float* __restrict__ Sd2, float* __restrict__ Sm)
{
    __shared__ short smem[32768];          // 64 KB
    short* d1L = smem;                     // 32 KB  (din1 tile 128x128 bf16; reuse)
    short* d2L = smem + 16384;             // 32 KB  (din2 tile; reuse)

    const int nt = blockIdx.x;             // 0..3   h-tile
    const int mt = blockIdx.y;             // 0..511 m-tile
    const int b  = mt >> 3;
    const int t0 = (mt & 7) << 7;

    const int tid = threadIdx.x, l = tid & 63, wv = tid >> 6;   // 8 waves
    const int ln = l & 15, qd = l >> 4;
    const int wm = (wv & 1) << 6;          // m-half: 0 / 64
    const int wn = (wv >> 1) << 5;         // n-quarter: 0/32/64/96

    const unsigned short* abase  = xb + (size_t)(mt * 128) * D_;
    const unsigned short* w1base = w1b + (size_t)(nt * 128) * HALF_;
    const unsigned short* w2base = w2b + (size_t)(nt * 128) * HALF_;

    // DMA indices (per thread, constant across rounds)
    const int kb = wv >> 1;                       // chunk 0..3
    const int rr = ((wv & 1) << 6) + l;           // row 0..127
    const int dst = wv * 512 + l * 8;             // shorts within a tile

    f32x4 acc0[4][2] = {};
    f32x4 acc1[4][2] = {};

    auto stage = [&](int kt, int ph) {
        short* p = smem + ph * 16384;
        gl_lds16(abase  + (size_t)rr * D_    + kt + kb * 8,         p + dst);
        gl_lds16(abase  + (size_t)rr * D_    + HALF_ + kt + kb * 8, p + 4096  + dst);
        gl_lds16(w1base + (size_t)rr * HALF_ + kt + kb * 8,         p + 8192  + dst);
        gl_lds16(w2base + (size_t)rr * HALF_ + kt + kb * 8,         p + 12288 + dst);
    };

    // prologue: two stages in flight
    stage(0, 0);
    stage(32, 1);

    #pragma unroll
    for (int t = 0; t < 8; ++t) {
        const int ph = t & 1;
        short* base = smem + ph * 16384;
        // wait for stage(t) only; stage(t+1)'s 4 loads stay outstanding
        if (t < 7) { asm volatile("s_waitcnt vmcnt(4)" ::: "memory"); }
        else       { asm volatile("s_waitcnt vmcnt(0)" ::: "memory"); }
        __builtin_amdgcn_s_barrier();
        // compute round t (branch 1 then branch 2), 16 MFMA/wave
        {
            s16x8 af[4], bfv[2];
            #pragma unroll
            for (int i = 0; i < 4; ++i)
                af[i] = *(const s16x8*)&base[qd * 1024 + (wm + i * 16 + ln) * 8];
            #pragma unroll
            for (int j = 0; j < 2; ++j)
                bfv[j] = *(const s16x8*)&base[8192 + qd * 1024 + (wn + j * 16 + ln) * 8];
            #pragma unroll
            for (int i = 0; i < 4; ++i)
                #pragma unroll
                for (int j = 0; j < 2; ++j)
                    acc0[i][j] = __builtin_amdgcn_mfma_f32_16x16x32_bf16(
                        af[i], bfv[j], acc0[i][j], 0, 0, 0);
            #pragma unroll
            for (int i = 0; i < 4; ++i)
                af[i] = *(const s16x8*)&base[4096 + qd * 1024 + (wm + i * 16 + ln) * 8];
            #pragma unroll
            for (int j = 0; j < 2; ++j)
                bfv[j] = *(const s16x8*)&base[12288 + qd * 1024 + (wn + j * 16 + ln) * 8];
            #pragma unroll
            for (int i = 0; i < 4; ++i)
                #pragma unroll
                for (int j = 0; j < 2; ++j)
                    acc1[i][j] = __builtin_amdgcn_mfma_f32_16x16x32_bf16(
                        af[i], bfv[j], acc1[i][j], 0, 0, 0);
        }
        __builtin_amdgcn_s_barrier();          // all waves done reading phase ph
        if (t < 6) stage((t + 2) * 32, ph);    // refill ph for round t+2
    }

    // dump din tiles to LDS: [t][h ^ ((t&12)<<2)], bf16 (swizzle kills qd-group conflicts)
    #pragma unroll
    for (int i = 0; i < 4; ++i)
        #pragma unroll
        for (int j = 0; j < 2; ++j)
            #pragma unroll
            for (int r = 0; r < 4; ++r) {
                int t  = wm + i * 16 + qd * 4 + r;
                int hc = (wn + j * 16 + ln) ^ ((t & 12) << 2);
                d1L[t * 128 + hc] = (short)f2bf(acc0[i][j][r]);
                d2L[t * 128 + hc] = (short)f2bf(acc1[i][j][r]);
            }
    __syncthreads();

    // local chunk scans: thread = (chunk cl = tid>>7, single h = tid&127)
    const int cl = tid >> 7;               // 0..3
    const int h  = tid & 127;              // 0..127
    const int hg = nt * 128 + h;
    const int cg = ((mt & 7) << 2) + cl;

    const float a1 = sigf(tau1[hg]);
    const float a2 = sigf(tau2[hg]);
    const float o1 = 1.f - a1, o2 = 1.f - a2;
    const float bb1 = b1[hg], bb2 = b2[hg];

    float d1 = 0.f, d2 = 0.f, m = 0.f;
    unsigned short* msh = (unsigned short*)mems;
    const size_t mrow = (size_t)(b * T_ + t0 + cl * CLEN) * H_ + hg;

    #pragma unroll 8
    for (int k = 0; k < CLEN; ++k) {
        int t  = cl * CLEN + k;
        int hc = h ^ ((t & 12) << 2);
        float i1 = bfu16((unsigned short)d1L[t * 128 + hc]) + bb1;
        float i2 = bfu16((unsigned short)d2L[t * 128 + hc]) + bb2;
        d1 = a1 * d1 + o1 * i1;
        d2 = a2 * d2 + o2 * i2;
        m  = 0.8f * m + 0.2f * (d1 + d2);
        msh[mrow + (size_t)k * H_] = f2bf(m);
    }

    const size_t si = (size_t)(cg * B_ + b) * H_ + hg;
    Sd1[si] = d1;
    Sd2[si] = d2;
    Sm[si]  = m;
}

// ---------------- scanB: sequential chunk-state combine (writes c=0 zeros) ---------------
__global__ __launch_bounds__(128) void scanB_kernel(
    const float* __restrict__ Sd1, const float* __restrict__ Sd2,
    const float* __restrict__ Sm,
    const float* __restrict__ tau1, const float* __restrict__ tau2,
    float* __restrict__ D1, float* __restrict__ D2, float* __restrict__ DM)
{
    const int g = blockIdx.x * 128 + threadIdx.x;  // 0..16383
    const int h2 = g & 255, b = g >> 8, h0 = h2 << 1;

    const float a1a = sigf(tau1[h0]), a1b = sigf(tau1[h0 + 1]);
    const float a2a = sigf(tau2[h0]), a2b = sigf(tau2[h0 + 1]);
    const float amL = pw32(0.8f);
    const float a1La = pw32(a1a), a1Lb = pw32(a1b);
    const float a2La = pw32(a2a), a2Lb = pw32(a2b);

    const float c1a = 0.2f * a1a / guard(0.8f - a1a);
    const float c1b = 0.2f * a1b / guard(0.8f - a1b);
    const float c2a = 0.2f * a2a / guard(0.8f - a2a);
    const float c2b = 0.2f * a2b / guard(0.8f - a2b);

    const float g1La = c1a * (amL - a1La), g1Lb = c1b * (amL - a1Lb);
    const float g2La = c2a * (amL - a2La), g2Lb = c2b * (amL - a2Lb);

    float D1a = 0.f, D1b = 0.f, D2a = 0.f, D2b = 0.f, Ma = 0.f, Mb = 0.f;
    for (int c = 0; c < NC; ++c) {
        const size_t si = (size_t)(c * B_ + b) * H_ + h0;
        f32x2 v;
        v.x = D1a; v.y = D1b; *(f32x2*)&D1[si] = v;
        v.x = D2a; v.y = D2b; *(f32x2*)&D2[si] = v;
        v.x = Ma;  v.y = Mb;  *(f32x2*)&DM[si] = v;
        f32x2 s1 = *(const f32x2*)&Sd1[si];
        f32x2 s2 = *(const f32x2*)&Sd2[si];
        f32x2 sm = *(const f32x2*)&Sm[si];
        float nMa = amL * Ma + D1a * g1La + D2a * g2La + sm.x;
        float nMb = amL * Mb + D1b * g1Lb + D2b * g2Lb + sm.y;
        D1a = a1La * D1a + s1.x;  D1b = a1Lb * D1b + s1.y;
        D2a = a2La * D2a + s2.x;  D2b = a2Lb * D2b + s2.y;
        Ma = nMa;  Mb = nMb;
    }
}

// ---------------- gemm2f: 8-wave blocks, fix-up in A-staging + MFMA + sigmoid ------------
__global__ __launch_bounds__(512, 4) void gemm2f_kernel(
    const unsigned short* __restrict__ mems, const unsigned short* __restrict__ wob,
    const float* __restrict__ bo,
    const float* __restrict__ G1, const float* __restrict__ G2,
    const float* __restrict__ D1, const float* __restrict__ D2,
    const float* __restrict__ DM, float* __restrict__ out)
{
    __shared__ short As[128 * 64];
    __shared__ short Bs[128 * 64];
    __shared__ float PMl[CLEN];

    const int mt = blockIdx.x;
    const int b = mt >> 3, c0 = (mt & 7) << 2;
    const int tid = threadIdx.x, l = tid & 63, wv = tid >> 6;   // 8 waves
    const int ln = l & 15, qd = l >> 4;
    const int wm = (wv & 1) << 6;          // m-half
    const int wn = (wv >> 1) << 5;         // o-quarter

    if (tid < CLEN) {
        float pm = 1.f;
        for (int k = 0; k <= tid; ++k) pm *= 0.8f;
        PMl[tid] = pm;                       // 0.8^{k+1}
    }
    __syncthreads();

    f32x4 acc[4][2] = {};
    const unsigned short* abase = mems + (size_t)(mt * 128) * H_;

    for (int kt = 0; kt < H_; kt += 64) {
        // B staging: async DMA from pre-cast bf16 wo
        #pragma unroll
        for (int i = 0; i < 2; ++i) {
            int ch = wv * 2 + i;
            int r  = ch * 8 + (l >> 3);
            int kbl = (l & 7) ^ (r & 7);
            gl_lds16(wob + (size_t)r * H_ + kt + kbl * 8, &Bs[ch * 512 + l * 8]);
        }
        // A staging with fix-up (VALU)
        #pragma unroll
        for (int i = 0; i < 2; ++i) {
            int gi = i * 512 + tid;
            int r = gi >> 3, kbp = gi & 7, kbl = kbp ^ (r & 7);
            int h0 = kt + kbl * 8;
            int k = r & 31, c = c0 + (r >> 5);
            size_t dbase = (size_t)(c * B_ + b) * H_ + h0;
            f32x4 d1a = *(const f32x4*)&D1[dbase], d1b = *(const f32x4*)&D1[dbase + 4];
            f32x4 d2a = *(const f32x4*)&D2[dbase], d2b = *(const f32x4*)&D2[dbase + 4];
            f32x4 dma = *(const f32x4*)&DM[dbase], dmb = *(const f32x4*)&DM[dbase + 4];
            f32x4 g1a = *(const f32x4*)&G1[k * H_ + h0], g1b = *(const f32x4*)&G1[k * H_ + h0 + 4];
            f32x4 g2a = *(const f32x4*)&G2[k * H_ + h0], g2b = *(const f32x4*)&G2[k * H_ + h0 + 4];
            float pm = PMl[k];
            u32x4 mv = *(const u32x4*)(abase + (size_t)r * H_ + h0);
            float v0 = bflo(mv.x) + d1a.x * g1a.x + d2a.x * g2a.x + dma.x * pm;
            float v1 = bfhi(mv.x) + d1a.y * g1a.y + d2a.y * g2a.y + dma.y * pm;
            float v2 = bflo(mv.y) + d1a.z * g1a.z + d2a.z * g2a.z + dma.z * pm;
            float v3 = bfhi(mv.y) + d1a.w * g1a.w + d2a.w * g2a.w + dma.w * pm;
            float v4 = bflo(mv.z) + d1b.x * g1b.x + d2b.x * g2b.x + dmb.x * pm;
            float v5 = bfhi(mv.z) + d1b.y * g1b.y + d2b.y * g2b.y + dmb.y * pm;
            float v6 = bflo(mv.w) + d1b.z * g1b.z + d2b.z * g2b.z + dmb.z * pm;
            float v7 = bfhi(mv.w) + d1b.w * g1b.w + d2b.w * g2b.w + dmb.w * pm;
            u32x4 p;
            p.x = packbf(v0, v1); p.y = packbf(v2, v3);
            p.z = packbf(v4, v5); p.w = packbf(v6, v7);
            *(u32x4*)&As[r * 64 + kbp * 8] = p;
        }
        __syncthreads();
        #pragma unroll
        for (int ks = 0; ks < 64; ks += 32) {
            s16x8 af[4], bfv[2];
            #pragma unroll
            for (int i = 0; i < 4; ++i) {
                int r = wm + i * 16 + ln;
                int kbp = ((ks >> 3) + qd) ^ (r & 7);
                af[i] = *(const s16x8*)&As[r * 64 + kbp * 8];
            }
            #pragma unroll
            for (int j = 0; j < 2; ++j) {
                int r = wn + j * 16 + ln;
                int kbp = ((ks >> 3) + qd) ^ (r & 7);
                bfv[j] = *(const s16x8*)&Bs[r * 64 + kbp * 8];
            }
            #pragma unroll
            for (int i = 0; i < 4; ++i)
                #pragma unroll
                for (int j = 0; j < 2; ++j)
                    acc[i][j] = __builtin_amdgcn_mfma_f32_16x16x32_bf16(
                        af[i], bfv[j], acc[i][j], 0, 0, 0);
        }
        __syncthreads();
    }

    float bov[2];
    #pragma unroll
    for (int j = 0; j < 2; ++j) bov[j] = bo[wn + j * 16 + ln];

    float* orow = out + (size_t)(mt * 128 + wm + qd * 4) * O_ + wn + ln;
    #pragma unroll
    for (int i = 0; i < 4; ++i)
        #pragma unroll
        for (int j = 0; j < 2; ++j)
            #pragma unroll
            for (int r = 0; r < 4; ++r) {
                float v = acc[i][j][r] + bov[j];
                orow[(size_t)(i * 16 + r) * O_ + j * 16] = 1.f / (1.f + __expf(-v));
            }
}

extern "C" void kernel_launch(void* const* d_in, const int* in_sizes, int n_in,
                              void* d_out, int out_size, void* d_ws, size_t ws_size,
                              hipStream_t stream) {
    const float* x    = (const float*)d_in[0];
    const float* w1   = (const float*)d_in[1];
    const float* b1   = (const float*)d_in[2];
    const float* tau1 = (const float*)d_in[3];
    const float* w2   = (const float*)d_in[4];
    const float* b2   = (const float*)d_in[5];
    const float* tau2 = (const float*)d_in[6];
    const float* wo   = (const float*)d_in[7];
    const float* bo   = (const float*)d_in[8];
    float* out = (float*)d_out;

    // ws layout:
    //  [0,64Mi)   xb bf16
    //  [64,128Mi) mems bf16
    //  [128Mi..)  Sd1,Sd2,Sm,D1,D2,DM (1M f32 each = 24 MiB), G1,G2 (64 KB each),
    //             w1b,w2b (256 KB each bf16), wob (128 KB bf16)
    char* w = (char*)d_ws;
    unsigned short* xb   = (unsigned short*)(w);
    unsigned int*   mems = (unsigned int*)(w + (size_t)64 * 1024 * 1024);
    float* Sd1 = (float*)(w + (size_t)128 * 1024 * 1024);
    float* Sd2 = Sd1 + (1u << 20);
    float* Sm  = Sd1 + (2u << 20);
    float* D1  = Sd1 + (3u << 20);
    float* D2  = Sd1 + (4u << 20);
    float* DM  = Sd1 + (5u << 20);
    float* G1  = Sd1 + (6u << 20);
    float* G2  = G1 + CLEN * H_;
    unsigned short* w1b = (unsigned short*)(G2 + CLEN * H_);
    unsigned short* w2b = w1b + (size_t)H_ * HALF_;
    unsigned short* wob = w2b + (size_t)H_ * HALF_;

    gtab_kernel<<<dim3(2), 256, 0, stream>>>(tau1, tau2, G1, G2);
    wcast_kernel<<<dim3(128, 3), 256, 0, stream>>>(w1, w2, wo,
                                                   (unsigned int*)w1b,
                                                   (unsigned int*)w2b,
                                                   (unsigned int*)wob);
    cast_kernel<<<dim3(16384), 256, 0, stream>>>(x, (unsigned int*)xb);
    gemm1f_kernel<<<dim3(4, 512), 512, 0, stream>>>(xb, w1b, w2b, b1, tau1, b2, tau2,
                                                    mems, Sd1, Sd2, Sm);
    scanB_kernel<<<dim3(128), 128, 0, stream>>>(Sd1, Sd2, Sm, tau1, tau2, D1, D2, DM);
    gemm2f_kernel<<<dim3(512), 512, 0, stream>>>((const unsigned short*)mems, wob, bo,
                                                 G1, G2, D1, D2, DM, out);
}

// Round 9
// 341.484 us; speedup vs baseline: 1.0862x; 1.0862x over previous
//
#include <hip/hip_runtime.h>

// B=64 T=1024 D=512 H=512 O=128 HALF=256 ALPHA_M=0.8
// Pipeline:
//   gtab   : fix-up coefficient tables G1/G2 [32][512] f32
//   wcast  : w1/w2/wo fp32 -> bf16 (one-time)
//   cast   : x fp32 -> xb bf16
//   gemm1f : 8-wave, BK=32, 2-phase staging with COUNTED vmcnt(4) AND coalesced
//            DMA (16 rows x 64 B contiguous per wave-instruction; pos-swizzled
//            [row][(kc+(row>>1))&3][8] LDS layout, conflict-free ds_read_b128)
//            + in-LDS chunk scan -> mems + chunk states.
//   scanB  : sequential chunk-state combine -> D1/D2/DM prefix states
//   gemm2f : 8-wave blocks: fix-up in A-staging + MFMA + bias + sigmoid -> out fp32

#define B_    64
#define T_    1024
#define D_    512
#define H_    512
#define O_    128
#define HALF_ 256
#define CLEN  32
#define NC    32

typedef __attribute__((ext_vector_type(4))) float        f32x4;
typedef __attribute__((ext_vector_type(2))) float        f32x2;
typedef __attribute__((ext_vector_type(8))) short        s16x8;
typedef __attribute__((ext_vector_type(4))) unsigned int u32x4;
typedef __attribute__((ext_vector_type(2))) unsigned int u32x2;

__device__ __forceinline__ unsigned short f2bf(float f) {
    unsigned u = __float_as_uint(f);
    return (unsigned short)((u + 0x7fffu + ((u >> 16) & 1u)) >> 16);  // RNE
}
__device__ __forceinline__ unsigned packbf(float a, float b) {
    return (unsigned)f2bf(a) | ((unsigned)f2bf(b) << 16);
}
__device__ __forceinline__ float bflo(unsigned u) { return __uint_as_float(u << 16); }
__device__ __forceinline__ float bfu16(unsigned short u) {
    return __uint_as_float(((unsigned)u) << 16);
}
__device__ __forceinline__ float bfhi(unsigned u) { return __uint_as_float(u & 0xffff0000u); }
__device__ __forceinline__ float sigf(float x) { return 1.f / (1.f + __expf(-x)); }
__device__ __forceinline__ float guard(float dn) {
    if (fabsf(dn) < 1e-6f) dn = (dn < 0.f ? -1e-6f : 1e-6f);
    return dn;
}
__device__ __forceinline__ float pw32(float a) {  // a^32
    float t = a * a; t *= t; t *= t; t *= t; t *= t; return t;
}

typedef const __attribute__((address_space(1))) unsigned int gu32;
typedef __attribute__((address_space(3))) unsigned int      lu32;
__device__ __forceinline__ void gl_lds16(const void* g, void* l) {
    __builtin_amdgcn_global_load_lds((gu32*)g, (lu32*)l, 16, 0, 0);
}

// ---------------- gtab: G1[k][h] = c1(h)*(0.8^{k+1} - a1(h)^{k+1}), same G2 --------------
__global__ __launch_bounds__(256) void gtab_kernel(
    const float* __restrict__ tau1, const float* __restrict__ tau2,
    float* __restrict__ G1, float* __restrict__ G2)
{
    const int h = blockIdx.x * 256 + threadIdx.x;   // 0..511
    const float a1 = sigf(tau1[h]), a2 = sigf(tau2[h]);
    const float c1 = 0.2f * a1 / guard(0.8f - a1);
    const float c2 = 0.2f * a2 / guard(0.8f - a2);
    float pm = 1.f, p1 = 1.f, p2 = 1.f;
    for (int k = 0; k < CLEN; ++k) {
        pm *= 0.8f; p1 *= a1; p2 *= a2;
        G1[k * H_ + h] = c1 * (pm - p1);
        G2[k * H_ + h] = c2 * (pm - p2);
    }
}

// ---------------- wcast: w1/w2/wo fp32 -> bf16 packed (bit-identical RNE) ----------------
__global__ __launch_bounds__(256) void wcast_kernel(
    const float* __restrict__ w1, const float* __restrict__ w2,
    const float* __restrict__ wo,
    unsigned int* __restrict__ w1b, unsigned int* __restrict__ w2b,
    unsigned int* __restrict__ wob)
{
    const float* s; unsigned int* d; int n;
    if (blockIdx.y == 0)      { s = w1; d = w1b; n = H_ * HALF_; }
    else if (blockIdx.y == 1) { s = w2; d = w2b; n = H_ * HALF_; }
    else                      { s = wo; d = wob; n = O_ * H_;    }
    int i = (blockIdx.x * 256 + threadIdx.x) * 4;
    if (i >= n) return;
    f32x4 a = *(const f32x4*)(s + i);
    u32x2 p;
    p.x = packbf(a.x, a.y);
    p.y = packbf(a.z, a.w);
    *(u32x2*)(d + i / 2) = p;
}

// ---------------- cast: x fp32 -> xb bf16 (packed) ---------------------------------------
__global__ __launch_bounds__(256) void cast_kernel(const float* __restrict__ x,
                                                   unsigned int* __restrict__ xb) {
    size_t i = ((size_t)blockIdx.x * 256 + threadIdx.x) * 8;
    f32x4 a = *(const f32x4*)(x + i);
    f32x4 b = *(const f32x4*)(x + i + 4);
    u32x4 p;
    p.x = packbf(a.x, a.y); p.y = packbf(a.z, a.w);
    p.z = packbf(b.x, b.y); p.w = packbf(b.z, b.w);
    *(u32x4*)(xb + i / 2) = p;
}

// ---------------- gemm1f: BK=32 2-phase, counted vmcnt, COALESCED staging ----------------
// Phase layout (shorts, 16384/phase = 32 KB): A1 [0,4096) A2 [4096,8192)
// B1 [8192,12288) B2 [12288,16384).
// Tile layout: [row 0..127][pos 0..3][8 shorts]; pos p holds source k-chunk
// kc = (p - (row>>1)) & 3. DMA: thread tid loads row tid>>2, dest pos tid&3
// -> each wave reads 16 rows x 64 B CONTIGUOUS (16 segments/instr) and writes
// wave_base + lane*16B (linear). ds_read: chunk qd of row r at pos
// (qd+(r>>1))&3 -> uniform 8 lanes per 4-bank quad = conflict-free minimum.
// Pipeline: vmcnt(4) waits stage(t) only; stage(t+1) stays in flight across
// the barrier (never vmcnt(0) in the main loop).
__global__ __launch_bounds__(512, 4) void gemm1f_kernel(
    const unsigned short* __restrict__ xb,
    const unsigned short* __restrict__ w1b, const unsigned short* __restrict__ w2b,
    const float* __restrict__ b1, const float* __restrict__ tau1,
    const float* __restrict__ b2, const float* __restrict__ tau2,
    unsigned int* __restrict__ mems,
    float* __restrict__ Sd1, float* __restrict__ Sd2, float* __restrict__ Sm)
{
    __shared__ short smem[32768];          // 64 KB
    short* d1L = smem;                     // 32 KB  (din1 tile 128x128 bf16; reuse)
    short* d2L = smem + 16384;             // 32 KB  (din2 tile; reuse)

    const int nt = blockIdx.x;             // 0..3   h-tile
    const int mt = blockIdx.y;             // 0..511 m-tile
    const int b  = mt >> 3;
    const int t0 = (mt & 7) << 7;

    const int tid = threadIdx.x, l = tid & 63, wv = tid >> 6;   // 8 waves
    const int ln = l & 15, qd = l >> 4;
    const int wm = (wv & 1) << 6;          // m-half: 0 / 64
    const int wn = (wv >> 1) << 5;         // n-quarter: 0/32/64/96

    const unsigned short* abase  = xb + (size_t)(mt * 128) * D_;
    const unsigned short* w1base = w1b + (size_t)(nt * 128) * HALF_;
    const unsigned short* w2base = w2b + (size_t)(nt * 128) * HALF_;

    // coalesced DMA indices (per thread, constant across rounds)
    const int srow = tid >> 2;                    // row 0..127
    const int spos = tid & 3;                     // dest chunk position
    const int skc  = (spos - (srow >> 1)) & 3;    // source k-chunk at that pos
    const int sdst = wv * 512 + l * 8;            // == srow*32 + spos*8

    f32x4 acc0[4][2] = {};
    f32x4 acc1[4][2] = {};

    auto stage = [&](int kt, int ph) {
        short* p = smem + ph * 16384;
        const int acol = kt + skc * 8;
        gl_lds16(abase  + (size_t)srow * D_    + acol,         p + sdst);
        gl_lds16(abase  + (size_t)srow * D_    + HALF_ + acol, p + 4096  + sdst);
        gl_lds16(w1base + (size_t)srow * HALF_ + acol,         p + 8192  + sdst);
        gl_lds16(w2base + (size_t)srow * HALF_ + acol,         p + 12288 + sdst);
    };

    // prologue: two stages in flight
    stage(0, 0);
    stage(32, 1);

    #pragma unroll
    for (int t = 0; t < 8; ++t) {
        const int ph = t & 1;
        short* base = smem + ph * 16384;
        // wait for stage(t) only; stage(t+1)'s 4 loads stay outstanding
        if (t < 7) { asm volatile("s_waitcnt vmcnt(4)" ::: "memory"); }
        else       { asm volatile("s_waitcnt vmcnt(0)" ::: "memory"); }
        __builtin_amdgcn_s_barrier();
        // compute round t (branch 1 then branch 2), 16 MFMA/wave
        {
            s16x8 af[4], bfv[2];
            #pragma unroll
            for (int i = 0; i < 4; ++i) {
                int r = wm + i * 16 + ln;
                int pos = (qd + (r >> 1)) & 3;
                af[i] = *(const s16x8*)&base[r * 32 + pos * 8];
            }
            #pragma unroll
            for (int j = 0; j < 2; ++j) {
                int r = wn + j * 16 + ln;
                int pos = (qd + (r >> 1)) & 3;
                bfv[j] = *(const s16x8*)&base[8192 + r * 32 + pos * 8];
            }
            #pragma unroll
            for (int i = 0; i < 4; ++i)
                #pragma unroll
                for (int j = 0; j < 2; ++j)
                    acc0[i][j] = __builtin_amdgcn_mfma_f32_16x16x32_bf16(
                        af[i], bfv[j], acc0[i][j], 0, 0, 0);
            #pragma unroll
            for (int i = 0; i < 4; ++i) {
                int r = wm + i * 16 + ln;
                int pos = (qd + (r >> 1)) & 3;
                af[i] = *(const s16x8*)&base[4096 + r * 32 + pos * 8];
            }
            #pragma unroll
            for (int j = 0; j < 2; ++j) {
                int r = wn + j * 16 + ln;
                int pos = (qd + (r >> 1)) & 3;
                bfv[j] = *(const s16x8*)&base[12288 + r * 32 + pos * 8];
            }
            #pragma unroll
            for (int i = 0; i < 4; ++i)
                #pragma unroll
                for (int j = 0; j < 2; ++j)
                    acc1[i][j] = __builtin_amdgcn_mfma_f32_16x16x32_bf16(
                        af[i], bfv[j], acc1[i][j], 0, 0, 0);
        }
        __builtin_amdgcn_s_barrier();          // all waves done reading phase ph
        if (t < 6) stage((t + 2) * 32, ph);    // refill ph for round t+2
    }

    // dump din tiles to LDS: [t][h ^ ((t&12)<<2)], bf16 (swizzle kills qd-group conflicts)
    #pragma unroll
    for (int i = 0; i < 4; ++i)
        #pragma unroll
        for (int j = 0; j < 2; ++j)
            #pragma unroll
            for (int r = 0; r < 4; ++r) {
                int t  = wm + i * 16 + qd * 4 + r;
                int hc = (wn + j * 16 + ln) ^ ((t & 12) << 2);
                d1L[t * 128 + hc] = (short)f2bf(acc0[i][j][r]);
                d2L[t * 128 + hc] = (short)f2bf(acc1[i][j][r]);
            }
    __syncthreads();

    // local chunk scans: thread = (chunk cl = tid>>7, single h = tid&127)
    const int cl = tid >> 7;               // 0..3
    const int h  = tid & 127;              // 0..127
    const int hg = nt * 128 + h;
    const int cg = ((mt & 7) << 2) + cl;

    const float a1 = sigf(tau1[hg]);
    const float a2 = sigf(tau2[hg]);
    const float o1 = 1.f - a1, o2 = 1.f - a2;
    const float bb1 = b1[hg], bb2 = b2[hg];

    float d1 = 0.f, d2 = 0.f, m = 0.f;
    unsigned short* msh = (unsigned short*)mems;
    const size_t mrow = (size_t)(b * T_ + t0 + cl * CLEN) * H_ + hg;

    #pragma unroll 8
    for (int k = 0; k < CLEN; ++k) {
        int t  = cl * CLEN + k;
        int hc = h ^ ((t & 12) << 2);
        float i1 = bfu16((unsigned short)d1L[t * 128 + hc]) + bb1;
        float i2 = bfu16((unsigned short)d2L[t * 128 + hc]) + bb2;
        d1 = a1 * d1 + o1 * i1;
        d2 = a2 * d2 + o2 * i2;
        m  = 0.8f * m + 0.2f * (d1 + d2);
        msh[mrow + (size_t)k * H_] = f2bf(m);
    }

    const size_t si = (size_t)(cg * B_ + b) * H_ + hg;
    Sd1[si] = d1;
    Sd2[si] = d2;
    Sm[si]  = m;
}

// ---------------- scanB: sequential chunk-state combine (writes c=0 zeros) ---------------
__global__ __launch_bounds__(128) void scanB_kernel(
    const float* __restrict__ Sd1, const float* __restrict__ Sd2,
    const float* __restrict__ Sm,
    const float* __restrict__ tau1, const float* __restrict__ tau2,
    float* __restrict__ D1, float* __restrict__ D2, float* __restrict__ DM)
{
    const int g = blockIdx.x * 128 + threadIdx.x;  // 0..16383
    const int h2 = g & 255, b = g >> 8, h0 = h2 << 1;

    const float a1a = sigf(tau1[h0]), a1b = sigf(tau1[h0 + 1]);
    const float a2a = sigf(tau2[h0]), a2b = sigf(tau2[h0 + 1]);
    const float amL = pw32(0.8f);
    const float a1La = pw32(a1a), a1Lb = pw32(a1b);
    const float a2La = pw32(a2a), a2Lb = pw32(a2b);

    const float c1a = 0.2f * a1a / guard(0.8f - a1a);
    const float c1b = 0.2f * a1b / guard(0.8f - a1b);
    const float c2a = 0.2f * a2a / guard(0.8f - a2a);
    const float c2b = 0.2f * a2b / guard(0.8f - a2b);

    const float g1La = c1a * (amL - a1La), g1Lb = c1b * (amL - a1Lb);
    const float g2La = c2a * (amL - a2La), g2Lb = c2b * (amL - a2Lb);

    float D1a = 0.f, D1b = 0.f, D2a = 0.f, D2b = 0.f, Ma = 0.f, Mb = 0.f;
    for (int c = 0; c < NC; ++c) {
        const size_t si = (size_t)(c * B_ + b) * H_ + h0;
        f32x2 v;
        v.x = D1a; v.y = D1b; *(f32x2*)&D1[si] = v;
        v.x = D2a; v.y = D2b; *(f32x2*)&D2[si] = v;
        v.x = Ma;  v.y = Mb;  *(f32x2*)&DM[si] = v;
        f32x2 s1 = *(const f32x2*)&Sd1[si];
        f32x2 s2 = *(const f32x2*)&Sd2[si];
        f32x2 sm = *(const f32x2*)&Sm[si];
        float nMa = amL * Ma + D1a * g1La + D2a * g2La + sm.x;
        float nMb = amL * Mb + D1b * g1Lb + D2b * g2Lb + sm.y;
        D1a = a1La * D1a + s1.x;  D1b = a1Lb * D1b + s1.y;
        D2a = a2La * D2a + s2.x;  D2b = a2Lb * D2b + s2.y;
        Ma = nMa;  Mb = nMb;
    }
}

// ---------------- gemm2f: 8-wave blocks, fix-up in A-staging + MFMA + sigmoid ------------
__global__ __launch_bounds__(512, 4) void gemm2f_kernel(
    const unsigned short* __restrict__ mems, const unsigned short* __restrict__ wob,
    const float* __restrict__ bo,
    const float* __restrict__ G1, const float* __restrict__ G2,
    const float* __restrict__ D1, const float* __restrict__ D2,
    const float* __restrict__ DM, float* __restrict__ out)
{
    __shared__ short As[128 * 64];
    __shared__ short Bs[128 * 64];
    __shared__ float PMl[CLEN];

    const int mt = blockIdx.x;
    const int b = mt >> 3, c0 = (mt & 7) << 2;
    const int tid = threadIdx.x, l = tid & 63, wv = tid >> 6;   // 8 waves
    const int ln = l & 15, qd = l >> 4;
    const int wm = (wv & 1) << 6;          // m-half
    const int wn = (wv >> 1) << 5;         // o-quarter

    if (tid < CLEN) {
        float pm = 1.f;
        for (int k = 0; k <= tid; ++k) pm *= 0.8f;
        PMl[tid] = pm;                       // 0.8^{k+1}
    }
    __syncthreads();

    f32x4 acc[4][2] = {};
    const unsigned short* abase = mems + (size_t)(mt * 128) * H_;

    for (int kt = 0; kt < H_; kt += 64) {
        // B staging: async DMA from pre-cast bf16 wo
        #pragma unroll
        for (int i = 0; i < 2; ++i) {
            int ch = wv * 2 + i;
            int r  = ch * 8 + (l >> 3);
            int kbl = (l & 7) ^ (r & 7);
            gl_lds16(wob + (size_t)r * H_ + kt + kbl * 8, &Bs[ch * 512 + l * 8]);
        }
        // A staging with fix-up (VALU)
        #pragma unroll
        for (int i = 0; i < 2; ++i) {
            int gi = i * 512 + tid;
            int r = gi >> 3, kbp = gi & 7, kbl = kbp ^ (r & 7);
            int h0 = kt + kbl * 8;
            int k = r & 31, c = c0 + (r >> 5);
            size_t dbase = (size_t)(c * B_ + b) * H_ + h0;
            f32x4 d1a = *(const f32x4*)&D1[dbase], d1b = *(const f32x4*)&D1[dbase + 4];
            f32x4 d2a = *(const f32x4*)&D2[dbase], d2b = *(const f32x4*)&D2[dbase + 4];
            f32x4 dma = *(const f32x4*)&DM[dbase], dmb = *(const f32x4*)&DM[dbase + 4];
            f32x4 g1a = *(const f32x4*)&G1[k * H_ + h0], g1b = *(const f32x4*)&G1[k * H_ + h0 + 4];
            f32x4 g2a = *(const f32x4*)&G2[k * H_ + h0], g2b = *(const f32x4*)&G2[k * H_ + h0 + 4];
            float pm = PMl[k];
            u32x4 mv = *(const u32x4*)(abase + (size_t)r * H_ + h0);
            float v0 = bflo(mv.x) + d1a.x * g1a.x + d2a.x * g2a.x + dma.x * pm;
            float v1 = bfhi(mv.x) + d1a.y * g1a.y + d2a.y * g2a.y + dma.y * pm;
            float v2 = bflo(mv.y) + d1a.z * g1a.z + d2a.z * g2a.z + dma.z * pm;
            float v3 = bfhi(mv.y) + d1a.w * g1a.w + d2a.w * g2a.w + dma.w * pm;
            float v4 = bflo(mv.z) + d1b.x * g1b.x + d2b.x * g2b.x + dmb.x * pm;
            float v5 = bfhi(mv.z) + d1b.y * g1b.y + d2b.y * g2b.y + dmb.y * pm;
            float v6 = bflo(mv.w) + d1b.z * g1b.z + d2b.z * g2b.z + dmb.z * pm;
            float v7 = bfhi(mv.w) + d1b.w * g1b.w + d2b.w * g2b.w + dmb.w * pm;
            u32x4 p;
            p.x = packbf(v0, v1); p.y = packbf(v2, v3);
            p.z = packbf(v4, v5); p.w = packbf(v6, v7);
            *(u32x4*)&As[r * 64 + kbp * 8] = p;
        }
        __syncthreads();
        #pragma unroll
        for (int ks = 0; ks < 64; ks += 32) {
            s16x8 af[4], bfv[2];
            #pragma unroll
            for (int i = 0; i < 4; ++i) {
                int r = wm + i * 16 + ln;
                int kbp = ((ks >> 3) + qd) ^ (r & 7);
                af[i] = *(const s16x8*)&As[r * 64 + kbp * 8];
            }
            #pragma unroll
            for (int j = 0; j < 2; ++j) {
                int r = wn + j * 16 + ln;
                int kbp = ((ks >> 3) + qd) ^ (r & 7);
                bfv[j] = *(const s16x8*)&Bs[r * 64 + kbp * 8];
            }
            #pragma unroll
            for (int i = 0; i < 4; ++i)
                #pragma unroll
                for (int j = 0; j < 2; ++j)
                    acc[i][j] = __builtin_amdgcn_mfma_f32_16x16x32_bf16(
                        af[i], bfv[j], acc[i][j], 0, 0, 0);
        }
        __syncthreads();
    }

    float bov[2];
    #pragma unroll
    for (int j = 0; j < 2; ++j) bov[j] = bo[wn + j * 16 + ln];

    float* orow = out + (size_t)(mt * 128 + wm + qd * 4) * O_ + wn + ln;
    #pragma unroll
    for (int i = 0; i < 4; ++i)
        #pragma unroll
        for (int j = 0; j < 2; ++j)
            #pragma unroll
            for (int r = 0; r < 4; ++r) {
                float v = acc[i][j][r] + bov[j];
                orow[(size_t)(i * 16 + r) * O_ + j * 16] = 1.f / (1.f + __expf(-v));
            }
}

extern "C" void kernel_launch(void* const* d_in, const int* in_sizes, int n_in,
                              void* d_out, int out_size, void* d_ws, size_t ws_size,
                              hipStream_t stream) {
    const float* x    = (const float*)d_in[0];
    const float* w1   = (const float*)d_in[1];
    const float* b1   = (const float*)d_in[2];
    const float* tau1 = (const float*)d_in[3];
    const float* w2   = (const float*)d_in[4];
    const float* b2   = (const float*)d_in[5];
    const float* tau2 = (const float*)d_in[6];
    const float* wo   = (const float*)d_in[7];
    const float* bo   = (const float*)d_in[8];
    float* out = (float*)d_out;

    // ws layout:
    //  [0,64Mi)   xb bf16
    //  [64,128Mi) mems bf16
    //  [128Mi..)  Sd1,Sd2,Sm,D1,D2,DM (1M f32 each = 24 MiB), G1,G2 (64 KB each),
    //             w1b,w2b (256 KB each bf16), wob (128 KB bf16)
    char* w = (char*)d_ws;
    unsigned short* xb   = (unsigned short*)(w);
    unsigned int*   mems = (unsigned int*)(w + (size_t)64 * 1024 * 1024);
    float* Sd1 = (float*)(w + (size_t)128 * 1024 * 1024);
    float* Sd2 = Sd1 + (1u << 20);
    float* Sm  = Sd1 + (2u << 20);
    float* D1  = Sd1 + (3u << 20);
    float* D2  = Sd1 + (4u << 20);
    float* DM  = Sd1 + (5u << 20);
    float* G1  = Sd1 + (6u << 20);
    float* G2  = G1 + CLEN * H_;
    unsigned short* w1b = (unsigned short*)(G2 + CLEN * H_);
    unsigned short* w2b = w1b + (size_t)H_ * HALF_;
    unsigned short* wob = w2b + (size_t)H_ * HALF_;

    gtab_kernel<<<dim3(2), 256, 0, stream>>>(tau1, tau2, G1, G2);
    wcast_kernel<<<dim3(128, 3), 256, 0, stream>>>(w1, w2, wo,
                                                   (unsigned int*)w1b,
                                                   (unsigned int*)w2b,
                                                   (unsigned int*)wob);
    cast_kernel<<<dim3(16384), 256, 0, stream>>>(x, (unsigned int*)xb);
    gemm1f_kernel<<<dim3(4, 512), 512, 0, stream>>>(xb, w1b, w2b, b1, tau1, b2, tau2,
                                                    mems, Sd1, Sd2, Sm);
    scanB_kernel<<<dim3(128), 128, 0, stream>>>(Sd1, Sd2, Sm, tau1, tau2, D1, D2, DM);
    gemm2f_kernel<<<dim3(512), 512, 0, stream>>>((const unsigned short*)mems, wob, bo,
                                                 G1, G2, D1, D2, DM, out);
}